// Round 5
// baseline (683.189 us; speedup 1.0000x reference)
//
#include <hip/hip_runtime.h>
#include <hip/hip_bf16.h>
#include <math.h>

#define IN_F   256
#define OUT_F  64
#define NSLICE 4
#define SLC    16      // cols per slice; slice table = N*16*2B = 3.2 MB -> fits 4MB XCD L2
#define PD     264     // w_t row stride in bf16 elems
#define CHROWS 64      // rows per work chunk in sliced spmm

typedef __attribute__((ext_vector_type(8))) short bf16x8;
typedef __attribute__((ext_vector_type(4))) float f32x4;
typedef __attribute__((ext_vector_type(2))) float f32x2;

__device__ inline unsigned short f2b(float x) {
    union { __hip_bfloat16 h; unsigned short u; } cv;
    cv.h = __float2bfloat16(x);
    return cv.u;
}
__device__ inline float b2f_lo(unsigned int u) { return __uint_as_float(u << 16); }
__device__ inline float b2f_hi(unsigned int u) { return __uint_as_float(u & 0xffff0000u); }

// ---------------------------------------------------------------------------
// K1: fused  (a) sup_bf = bf16(tanh(feat @ w)), (b) CSR row_ptr build,
// (c) zero the sliced-spmm work counters (must happen after harness poison,
// before spmm launches — stream order guarantees it).
// slice_major=1: sup_bf stored [NSLICE][N][SLC] so each XCD can pin its
// contiguous 3.2MB slice in L2. =0: node-major [N][64] for fallback spmm.
// ---------------------------------------------------------------------------
__global__ __launch_bounds__(512) void gemm_rowptr_kernel(
    const float* __restrict__ feat,      // [N, 256]
    const float* __restrict__ w,         // [256, 64]
    const int*  __restrict__ active,     // [1]
    const int*  __restrict__ rows,       // [E] sorted
    unsigned short* __restrict__ sup_bf,
    int* __restrict__ row_ptr,           // [N+1] or null
    int* __restrict__ ctr,               // [8] work counters or null
    int N, int E, int GB, int slice_major)
{
    __shared__ unsigned short wt[OUT_F * PD];   // 33792 B, wt[n*PD + k]

    if ((int)blockIdx.x >= GB) {
        // -------- edge-parallel row_ptr + counter zeroing --------
        if ((int)blockIdx.x == GB && threadIdx.x < 8 && ctr) ctr[threadIdx.x] = 0;
        int e = ((int)blockIdx.x - GB) * 512 + (int)threadIdx.x;
        if (e < E) {
            int r  = rows[e];
            int rn = (e + 1 < E) ? rows[e + 1] : N;
            if (e == 0) {
                for (int j = 0; j <= r; ++j) row_ptr[j] = 0;
            }
            for (int j = r + 1; j <= rn; ++j) row_ptr[j] = e + 1;
        }
        return;   // block-uniform branch: no barrier divergence
    }

    const int t = threadIdx.x;
    // stage weight: fp32 [k][n] -> bf16 transposed [n][k]
    #pragma unroll
    for (int r = 0; r < 8; ++r) {
        int f = r * 512 + t;              // float4 index, 0..4095
        float4 v = ((const float4*)w)[f];
        int k = f >> 4;                   // 4f/64
        int n = (f & 15) << 2;            // 4f%64
        wt[(n + 0) * PD + k] = f2b(v.x);
        wt[(n + 1) * PD + k] = f2b(v.y);
        wt[(n + 2) * PD + k] = f2b(v.z);
        wt[(n + 3) * PD + k] = f2b(v.w);
    }
    __syncthreads();

    const int lane = t & 63;
    const int m    = lane & 15;
    const int quad = lane >> 4;
    const int node0 = (int)blockIdx.x * 128 + (t >> 6) * 16;   // wave's m-tile

    int nd = node0 + m;
    if (nd > N - 1) nd = N - 1;           // clamp; OOB rows never stored
    const float* arow = feat + (size_t)nd * IN_F;

    f32x4 acc[4];                         // 4 n-tiles
    #pragma unroll
    for (int b = 0; b < 4; ++b) acc[b] = (f32x4)0.0f;

    #pragma unroll
    for (int kt = 0; kt < 8; ++kt) {
        const int ko = kt * 32 + quad * 8;
        f32x4 lo = __builtin_nontemporal_load((const f32x4*)(arow + ko));
        f32x4 hi = __builtin_nontemporal_load((const f32x4*)(arow + ko + 4));
        bf16x8 a;
        a[0] = (short)f2b(lo[0]); a[1] = (short)f2b(lo[1]);
        a[2] = (short)f2b(lo[2]); a[3] = (short)f2b(lo[3]);
        a[4] = (short)f2b(hi[0]); a[5] = (short)f2b(hi[1]);
        a[6] = (short)f2b(hi[2]); a[7] = (short)f2b(hi[3]);
        #pragma unroll
        for (int nt = 0; nt < 4; ++nt) {
            bf16x8 b = *(const bf16x8*)(&wt[(nt * 16 + m) * PD + ko]);
            acc[nt] = __builtin_amdgcn_mfma_f32_16x16x32_bf16(a, b, acc[nt], 0, 0, 0);
        }
    }

    int act = __builtin_amdgcn_readfirstlane(active[0]);
    #pragma unroll
    for (int r = 0; r < 4; ++r) {
        int node = node0 + quad * 4 + r;   // C/D: col=lane&15, row=quad*4+reg
        if (node >= N) continue;
        #pragma unroll
        for (int nt = 0; nt < 4; ++nt) {
            float v = acc[nt][r];
            if (act) v = tanhf(v);
            size_t idx = slice_major ? ((size_t)nt * N + node) * SLC + m
                                     : (size_t)node * OUT_F + nt * 16 + m;
            sup_bf[idx] = f2b(v);
        }
    }
}

// ---------------------------------------------------------------------------
// Sliced SpMM v2: XCD-pinned by HARDWARE id, not dispatch mapping.
//
// Each block reads its physical XCD via s_getreg(HW_REG_XCC_ID) [m09] and
// prefers slice = xcc>>1, pulling 64-row chunks from a per-slice atomic
// counter. All gathers then touch ONE contiguous 3.2MB slice table ->
// resident in that XCD's 4MB L2 (this is what round-4's blockIdx&7 mapping
// failed to deliver). Pass loop over all 4 slices guarantees completion even
// if XCC_ID were garbage (perf fallback, never wrong results).
// Meta (cols/vals, 4x replicated = 51MB) + row_ptr read NONTEMPORAL so the
// streams can't evict the pinned slice; streams run at ~6TB/s vs the 2.2TB/s
// random-miss ceiling that capped rounds 0-3.
// Wave geometry: 8 rows x 8 lanes (4B/lane covers the 32B slice row), zero
// cross-lane shuffles; 2 edges per iteration.
// ---------------------------------------------------------------------------
template <bool HASBF>
__global__ __launch_bounds__(256) void spmm_sliced_kernel(
    const int* __restrict__ row_ptr,          // [N+1]
    const int* __restrict__ cols,             // [E]
    const float* __restrict__ vals,           // [E]
    const unsigned short* __restrict__ xs,    // [NSLICE][N][SLC] bf16
    float* __restrict__ out,                  // [N,64] fp32 node-major
    unsigned short* __restrict__ out_bf,      // [NSLICE][N][SLC] or null
    int* __restrict__ ctr,                    // [NSLICE] work counters
    int N)
{
    unsigned int xcc;
    asm volatile("s_getreg_b32 %0, hwreg(HW_REG_XCC_ID)" : "=s"(xcc));
    const int myslice = (int)((xcc & 7u) >> 1);

    const int w    = threadIdx.x >> 6;
    const int lane = threadIdx.x & 63;
    const int g    = lane >> 3;     // row group 0..7 within wave
    const int p    = lane & 7;      // col pair within slice: cols {2p, 2p+1}
    const int nchunk = (N + CHROWS - 1) / CHROWS;

    __shared__ int ch;

    for (int pass = 0; pass < NSLICE; ++pass) {
        const int sl = (myslice + pass) & (NSLICE - 1);
        const unsigned short* xsl = xs + (size_t)sl * N * SLC;

        for (;;) {
            if (threadIdx.x == 0) ch = atomicAdd(&ctr[sl], 1);
            __syncthreads();
            const int chunk = ch;
            __syncthreads();
            if (chunk >= nchunk) break;

            #pragma unroll
            for (int r2 = 0; r2 < 2; ++r2) {
                const int row = chunk * CHROWS + r2 * 32 + w * 8 + g;
                if (row >= N) continue;
                const int s = __builtin_nontemporal_load(row_ptr + row);
                const int e = __builtin_nontemporal_load(row_ptr + row + 1);

                float a0 = 0.0f, a1 = 0.0f;
                for (int i = s; i < e; i += 2) {    // group-divergent, exec-masked
                    const int ib = (i + 1 < e) ? i + 1 : i;
                    const float va = __builtin_nontemporal_load(vals + i);
                    const float vb = (i + 1 < e) ? __builtin_nontemporal_load(vals + ib) : 0.0f;
                    const int   ca = __builtin_nontemporal_load(cols + i);
                    const int   cb = __builtin_nontemporal_load(cols + ib);
                    const unsigned int ga = *(const unsigned int*)(xsl + (size_t)ca * SLC + 2 * p);
                    const unsigned int gb = *(const unsigned int*)(xsl + (size_t)cb * SLC + 2 * p);
                    a0 = fmaf(va, b2f_lo(ga), a0); a1 = fmaf(va, b2f_hi(ga), a1);
                    a0 = fmaf(vb, b2f_lo(gb), a0); a1 = fmaf(vb, b2f_hi(gb), a1);
                }

                const size_t ob = (size_t)row * OUT_F + sl * SLC + 2 * p;
                f32x2 o = {a0, a1};
                __builtin_nontemporal_store(o, (f32x2*)(out + ob));
                if (HASBF) {
                    unsigned int pk = (unsigned int)f2b(a0) | ((unsigned int)f2b(a1) << 16);
                    *(unsigned int*)(out_bf + ((size_t)sl * N + row) * SLC + 2 * p) = pk;
                }
            }
        }
    }
}

// ---------------------------------------------------------------------------
// Generic fallback SpMM (node-major x), used only when workspace is too small.
// ---------------------------------------------------------------------------
__device__ inline int lower_bound(const int* __restrict__ a, int n, int key) {
    int lo = 0, hi = n;
    while (lo < hi) {
        int mid = (lo + hi) >> 1;
        if (a[mid] < key) lo = mid + 1; else hi = mid;
    }
    return lo;
}

template <bool XBF>
__global__ __launch_bounds__(256) void spmm_kernel(
    const int* __restrict__ row_ptr,
    const int* __restrict__ rows,
    const int* __restrict__ cols,
    const float* __restrict__ vals,
    const void* __restrict__ x,               // [N,64] bf16 or fp32 node-major
    float* __restrict__ out,
    unsigned short* __restrict__ out_bf,      // node-major or null
    int N, int E)
{
    const int lane = threadIdx.x & 63;
    const int h    = lane >> 5;
    const int l    = lane & 31;
    const int row  = blockIdx.x * 8 + (threadIdx.x >> 6) * 2 + h;

    const bool valid = row < N;
    const int  rc    = valid ? row : N - 1;

    int s, e;
    if (row_ptr) { s = row_ptr[rc]; e = row_ptr[rc + 1]; }
    else         { s = lower_bound(rows, E, rc); e = lower_bound(rows, E, rc + 1); }
    if (!valid) e = s;

    const unsigned short* xb = (const unsigned short*)x;
    const float*          xf = (const float*)x;

    float a0 = 0.0f, a1 = 0.0f;

    for (int base = s; base < e; base += 16) {
        int   c[16];
        float v[16];
        #pragma unroll
        for (int j = 0; j < 16; ++j) {
            int idx = base + j;
            int cl  = idx < e ? idx : e - 1;
            c[j] = cols[cl];
            v[j] = (idx < e) ? vals[cl] : 0.0f;
        }
        if (XBF) {
            #pragma unroll
            for (int j = 0; j < 16; ++j) {
                unsigned int g = *(const unsigned int*)(xb + (size_t)c[j] * OUT_F + 2 * l);
                a0 = fmaf(v[j], b2f_lo(g), a0);
                a1 = fmaf(v[j], b2f_hi(g), a1);
            }
        } else {
            #pragma unroll
            for (int j = 0; j < 16; ++j) {
                float2 g = *(const float2*)(xf + (size_t)c[j] * OUT_F + 2 * l);
                a0 = fmaf(v[j], g.x, a0);
                a1 = fmaf(v[j], g.y, a1);
            }
        }
    }

    if (valid) {
        size_t bidx = (size_t)row * OUT_F + 2 * l;
        f32x2 o = {a0, a1};
        __builtin_nontemporal_store(o, (f32x2*)(out + bidx));
        if (out_bf) {
            unsigned int pk = (unsigned int)f2b(a0) | ((unsigned int)f2b(a1) << 16);
            *(unsigned int*)(out_bf + bidx) = pk;
        }
    }
}

// ---------------------------------------------------------------------------
extern "C" void kernel_launch(void* const* d_in, const int* in_sizes, int n_in,
                              void* d_out, int out_size, void* d_ws, size_t ws_size,
                              hipStream_t stream) {
    const float* feat   = (const float*)d_in[0];   // [N,256] fp32
    const float* w      = (const float*)d_in[1];   // [256,64] fp32
    const int*   rows   = (const int*)d_in[2];     // [E] sorted
    const int*   cols   = (const int*)d_in[3];     // [E]
    const float* vals   = (const float*)d_in[4];   // [E] fp32
    const int*   active = (const int*)d_in[5];     // [1]

    const int N = in_sizes[0] / IN_F;   // 100000
    const int E = in_sizes[2];          // 1600000

    float* out = (float*)d_out;                    // [output | az] fp32
    float* az  = out + (size_t)N * OUT_F;

    // Workspace tiers
    size_t rp_bytes = (((size_t)(N + 1) * sizeof(int)) + 255) & ~(size_t)255;
    size_t bf_bytes = (((size_t)N * OUT_F * sizeof(unsigned short)) + 255) & ~(size_t)255;
    char* ws = (char*)d_ws;

    int* row_ptr = (ws_size >= rp_bytes) ? (int*)ws : nullptr;
    size_t used = row_ptr ? rp_bytes : 0;

    unsigned short* sup_bf;
    unsigned short* mid_bf = nullptr;   // bf16 copy of `output` for spmm2 gather
    int* ctr = nullptr;                 // [8] sliced-spmm work counters
    if (ws_size >= used + 2 * bf_bytes + 256) {
        sup_bf = (unsigned short*)(ws + used);
        mid_bf = (unsigned short*)(ws + used + bf_bytes);
        ctr    = (int*)(ws + used + 2 * bf_bytes);
    } else if (ws_size >= used + bf_bytes) {
        sup_bf = (unsigned short*)(ws + used);
    } else {
        sup_bf = (unsigned short*)az;   // az half of d_out as scratch
    }

    const int sliced = (row_ptr && mid_bf && ctr) ? 1 : 0;

    {   // fused: sup_bf = bf16(tanh(feat @ w)) + row_ptr build + ctr zero
        int GB = (N + 127) / 128;
        int RB = row_ptr ? (E + 511) / 512 : 0;
        gemm_rowptr_kernel<<<GB + RB, 512, 0, stream>>>(
            feat, w, active, rows, sup_bf, row_ptr, ctr, N, E, GB, sliced);
    }

    if (sliced) {
        const int sgrid = 2048;   // ~8 blocks/CU; self-scheduling via counters
        // output = A @ support  (xcc-pinned slice gathers; emit slice-major bf16)
        spmm_sliced_kernel<true><<<sgrid, 256, 0, stream>>>(
            row_ptr, cols, vals, sup_bf, out, mid_bf, ctr, N);
        // az = A @ output       (second counter set)
        spmm_sliced_kernel<false><<<sgrid, 256, 0, stream>>>(
            row_ptr, cols, vals, mid_bf, az, nullptr, ctr + 4, N);
    } else {
        int spmm_blocks = (N + 7) / 8;
        spmm_kernel<true><<<spmm_blocks, 256, 0, stream>>>(
            row_ptr, rows, cols, vals, sup_bf, out, nullptr, N, E);
        spmm_kernel<false><<<spmm_blocks, 256, 0, stream>>>(
            row_ptr, rows, cols, vals, out, az, nullptr, N, E);
    }
}

// Round 6
// 262.792 us; speedup vs baseline: 2.5997x; 2.5997x over previous
//
#include <hip/hip_runtime.h>
#include <hip/hip_bf16.h>
#include <math.h>

#define IN_F  256
#define OUT_F 64
#define PD    264      // w_t row stride in bf16 elems (264*2=528B: min-time b128 frag reads)

typedef __attribute__((ext_vector_type(8))) short bf16x8;
typedef __attribute__((ext_vector_type(4))) float f32x4;
typedef __attribute__((ext_vector_type(2))) float f32x2;

__device__ inline unsigned short f2b(float x) {
    union { __hip_bfloat16 h; unsigned short u; } cv;
    cv.h = __float2bfloat16(x);
    return cv.u;
}
__device__ inline float b2f_lo(unsigned int u) { return __uint_as_float(u << 16); }
__device__ inline float b2f_hi(unsigned int u) { return __uint_as_float(u & 0xffff0000u); }

// ---------------------------------------------------------------------------
// K1: fused  (a) sup_bf = bf16(tanh(feat @ w))  and  (b) CSR row_ptr build.
//
// gemm blocks [0,GB): 512 thr = 8 waves, wave owns one 16-node m-tile.
// feat reads are a 102 MB one-shot stream -> nontemporal loads so they don't
// evict the sup_bf table the following spmm gathers from L2/LLC.
// rowptr blocks [GB,GB+RB): edge-parallel scatter of row starts.
// ---------------------------------------------------------------------------
__global__ __launch_bounds__(512) void gemm_rowptr_kernel(
    const float* __restrict__ feat,      // [N, 256]
    const float* __restrict__ w,         // [256, 64]
    const int*  __restrict__ active,     // [1]
    const int*  __restrict__ rows,       // [E] sorted
    unsigned short* __restrict__ sup_bf, // [N, 64] bf16 bits
    int* __restrict__ row_ptr,           // [N+1] or null
    int N, int E, int GB)
{
    __shared__ unsigned short wt[OUT_F * PD];   // 33792 B, wt[n*PD + k]

    if ((int)blockIdx.x >= GB) {
        // -------- edge-parallel row_ptr --------
        int e = ((int)blockIdx.x - GB) * 512 + (int)threadIdx.x;
        if (e < E) {
            int r  = rows[e];
            int rn = (e + 1 < E) ? rows[e + 1] : N;
            if (e == 0) {
                for (int j = 0; j <= r; ++j) row_ptr[j] = 0;
            }
            for (int j = r + 1; j <= rn; ++j) row_ptr[j] = e + 1;
        }
        return;   // block-uniform branch: no barrier divergence
    }

    const int t = threadIdx.x;
    // stage weight: fp32 [k][n] -> bf16 transposed [n][k]
    #pragma unroll
    for (int r = 0; r < 8; ++r) {
        int f = r * 512 + t;              // float4 index, 0..4095
        float4 v = ((const float4*)w)[f];
        int k = f >> 4;                   // 4f/64
        int n = (f & 15) << 2;            // 4f%64
        wt[(n + 0) * PD + k] = f2b(v.x);
        wt[(n + 1) * PD + k] = f2b(v.y);
        wt[(n + 2) * PD + k] = f2b(v.z);
        wt[(n + 3) * PD + k] = f2b(v.w);
    }
    __syncthreads();

    const int lane = t & 63;
    const int m    = lane & 15;
    const int quad = lane >> 4;
    const int node0 = (int)blockIdx.x * 128 + (t >> 6) * 16;   // wave's m-tile

    int nd = node0 + m;
    if (nd > N - 1) nd = N - 1;           // clamp; OOB rows never stored
    const float* arow = feat + (size_t)nd * IN_F;

    f32x4 acc[4];                         // 4 n-tiles
    #pragma unroll
    for (int b = 0; b < 4; ++b) acc[b] = (f32x4)0.0f;

    #pragma unroll
    for (int kt = 0; kt < 8; ++kt) {
        const int ko = kt * 32 + quad * 8;
        f32x4 lo = __builtin_nontemporal_load((const f32x4*)(arow + ko));
        f32x4 hi = __builtin_nontemporal_load((const f32x4*)(arow + ko + 4));
        bf16x8 a;
        a[0] = (short)f2b(lo[0]); a[1] = (short)f2b(lo[1]);
        a[2] = (short)f2b(lo[2]); a[3] = (short)f2b(lo[3]);
        a[4] = (short)f2b(hi[0]); a[5] = (short)f2b(hi[1]);
        a[6] = (short)f2b(hi[2]); a[7] = (short)f2b(hi[3]);
        #pragma unroll
        for (int nt = 0; nt < 4; ++nt) {
            bf16x8 b = *(const bf16x8*)(&wt[(nt * 16 + m) * PD + ko]);
            acc[nt] = __builtin_amdgcn_mfma_f32_16x16x32_bf16(a, b, acc[nt], 0, 0, 0);
        }
    }

    int act = __builtin_amdgcn_readfirstlane(active[0]);
    #pragma unroll
    for (int r = 0; r < 4; ++r) {
        int node = node0 + quad * 4 + r;   // C/D: col=lane&15, row=quad*4+reg
        if (node >= N) continue;
        #pragma unroll
        for (int nt = 0; nt < 4; ++nt) {
            float v = acc[nt][r];
            if (act) v = tanhf(v);
            sup_bf[(size_t)node * OUT_F + nt * 16 + m] = f2b(v);
        }
    }
}

// ---------------------------------------------------------------------------
// SpMM: out[r,:] = sum_e vals[e] * x[cols[e],:]
//
// Two rows per wave: each 32-lane half owns one row, lane owns cols {2l,2l+1}
// -> acc[2], ZERO cross-lane shuffles. Per 16-edge batch: all 32 metadata
// loads hoisted (clamped + value-masked -> no tail code), then all 16
// gathers issued independently (16 random 128B lines in flight/wave, each
// line 100% utilized by the cooperative half-wave read), then the FMA chain.
// Critical path per row: meta -> gather -> fma = 2 latency exposures.
// Stores coalesced: 32 lanes x float2 = 256B.
// ---------------------------------------------------------------------------
__device__ inline int lower_bound(const int* __restrict__ a, int n, int key) {
    int lo = 0, hi = n;
    while (lo < hi) {
        int mid = (lo + hi) >> 1;
        if (a[mid] < key) lo = mid + 1; else hi = mid;
    }
    return lo;
}

template <bool XBF>
__global__ __launch_bounds__(256) void spmm_kernel(
    const int* __restrict__ row_ptr,          // [N+1] or null
    const int* __restrict__ rows,             // [E] sorted (fallback)
    const int* __restrict__ cols,             // [E]
    const float* __restrict__ vals,           // [E]
    const void* __restrict__ x,               // [N,64] bf16 or fp32
    float* __restrict__ out,                  // [N,64] fp32
    unsigned short* __restrict__ out_bf,      // [N,64] bf16 or null
    int N, int E)
{
    const int lane = threadIdx.x & 63;
    const int h    = lane >> 5;       // half -> which of the wave's 2 rows
    const int l    = lane & 31;       // lane in half -> cols {2l, 2l+1}
    const int row  = blockIdx.x * 8 + (threadIdx.x >> 6) * 2 + h;

    const bool valid = row < N;
    const int  rc    = valid ? row : N - 1;

    int s, e;
    if (row_ptr) { s = row_ptr[rc]; e = row_ptr[rc + 1]; }
    else         { s = lower_bound(rows, E, rc); e = lower_bound(rows, E, rc + 1); }
    if (!valid) e = s;

    const unsigned short* xb = (const unsigned short*)x;
    const float*          xf = (const float*)x;

    float a0 = 0.0f, a1 = 0.0f;

    for (int base = s; base < e; base += 16) {
        // ---- batch metadata: independent loads, clamped + masked ----
        int   c[16];
        float v[16];
        #pragma unroll
        for (int j = 0; j < 16; ++j) {
            int idx = base + j;
            int cl  = idx < e ? idx : e - 1;    // e > base >= s here, so e-1 valid
            c[j] = cols[cl];
            v[j] = (idx < e) ? vals[cl] : 0.0f;
        }
        // ---- 16 independent gathers, then FMA chain ----
        if (XBF) {
            #pragma unroll
            for (int j = 0; j < 16; ++j) {
                unsigned int g = *(const unsigned int*)(xb + (size_t)c[j] * OUT_F + 2 * l);
                a0 = fmaf(v[j], b2f_lo(g), a0);
                a1 = fmaf(v[j], b2f_hi(g), a1);
            }
        } else {
            #pragma unroll
            for (int j = 0; j < 16; ++j) {
                float2 g = *(const float2*)(xf + (size_t)c[j] * OUT_F + 2 * l);
                a0 = fmaf(v[j], g.x, a0);
                a1 = fmaf(v[j], g.y, a1);
            }
        }
    }

    if (valid) {
        size_t bidx = (size_t)row * OUT_F + 2 * l;
        f32x2 o = {a0, a1};
        __builtin_nontemporal_store(o, (f32x2*)(out + bidx));  // fp32 never gathered
        if (out_bf) {   // re-read by spmm2's gathers: keep cached
            unsigned int pk = (unsigned int)f2b(a0) | ((unsigned int)f2b(a1) << 16);
            *(unsigned int*)(out_bf + bidx) = pk;
        }
    }
}

// ---------------------------------------------------------------------------
extern "C" void kernel_launch(void* const* d_in, const int* in_sizes, int n_in,
                              void* d_out, int out_size, void* d_ws, size_t ws_size,
                              hipStream_t stream) {
    const float* feat   = (const float*)d_in[0];   // [N,256] fp32
    const float* w      = (const float*)d_in[1];   // [256,64] fp32
    const int*   rows   = (const int*)d_in[2];     // [E] sorted
    const int*   cols   = (const int*)d_in[3];     // [E]
    const float* vals   = (const float*)d_in[4];   // [E] fp32
    const int*   active = (const int*)d_in[5];     // [1]

    const int N = in_sizes[0] / IN_F;   // 100000
    const int E = in_sizes[2];          // 1600000

    float* out = (float*)d_out;                    // [output | az] fp32
    float* az  = out + (size_t)N * OUT_F;

    // Workspace tiers
    size_t rp_bytes = (((size_t)(N + 1) * sizeof(int)) + 255) & ~(size_t)255;
    size_t bf_bytes = (((size_t)N * OUT_F * sizeof(unsigned short)) + 255) & ~(size_t)255;
    char* ws = (char*)d_ws;

    int* row_ptr = (ws_size >= rp_bytes) ? (int*)ws : nullptr;
    size_t used = row_ptr ? rp_bytes : 0;

    unsigned short* sup_bf;
    unsigned short* mid_bf = nullptr;   // bf16 copy of `output` for spmm2 gather
    if (ws_size >= used + 2 * bf_bytes) {
        sup_bf = (unsigned short*)(ws + used);
        mid_bf = (unsigned short*)(ws + used + bf_bytes);
    } else if (ws_size >= used + bf_bytes) {
        sup_bf = (unsigned short*)(ws + used);
    } else {
        // az half of d_out as bf16 scratch (dead before spmm2 writes az)
        sup_bf = (unsigned short*)az;
    }

    {   // fused: sup_bf = bf16(tanh(feat @ w))  +  row_ptr build
        int GB = (N + 127) / 128;
        int RB = row_ptr ? (E + 511) / 512 : 0;
        gemm_rowptr_kernel<<<GB + RB, 512, 0, stream>>>(
            feat, w, active, rows, sup_bf, row_ptr, N, E, GB);
    }

    int spmm_blocks = (N + 7) / 8;   // 8 rows per 256-thread block (2 per wave)
    // output = A @ support   (gather bf16; also emit bf16 copy if we have room)
    spmm_kernel<true><<<spmm_blocks, 256, 0, stream>>>(
        row_ptr, rows, cols, vals, sup_bf, out, mid_bf, N, E);
    // az = A @ output
    if (mid_bf) {
        spmm_kernel<true><<<spmm_blocks, 256, 0, stream>>>(
            row_ptr, rows, cols, vals, mid_bf, az, nullptr, N, E);
    } else {
        spmm_kernel<false><<<spmm_blocks, 256, 0, stream>>>(
            row_ptr, rows, cols, vals, out, az, nullptr, N, E);
    }
}